// Round 2
// baseline (10650.951 us; speedup 1.0000x reference)
//
#include <hip/hip_runtime.h>

// Echo-state RNN, B=32, T=2048, NH=512, NI=NO=1.
// W_hh is ~90% exact zeros. One workgroup (CU) per batch; thread p owns the
// row at SORTED position p (rows sorted by nnz, descending), so each wave's
// gather trip count is its own local max (~55 avg) instead of the global
// padded max (88). Sparse rows live in registers; tanh(h) double-buffered in
// LDS; z via wave shuffle + cross-wave LDS reduce; 1 barrier/step.

#define NH   512
#define TT   2048
#define BB   32
#define PAD  88
#define PADH (PAD/2)

// ---------------------------------------------------------------------------
// A: nnz per row (wave-per-row ballot count)
// ---------------------------------------------------------------------------
__global__ __launch_bounds__(512) void count_nnz(
    const float* __restrict__ Whh, int* __restrict__ nnz) {
  const int wib  = threadIdx.x >> 6;
  const int lane = threadIdx.x & 63;
  const int row  = blockIdx.x * 8 + wib;
  const float* wrow = Whh + (size_t)row * NH;
  int cnt = 0;
  for (int c = 0; c < NH / 64; ++c)
    cnt += __popcll(__ballot(wrow[c * 64 + lane] != 0.0f));
  if (lane == 0) nnz[row] = cnt;
}

// ---------------------------------------------------------------------------
// B: rank rows by nnz descending (stable). perm[p] = row at sorted pos p.
// ---------------------------------------------------------------------------
__global__ __launch_bounds__(512) void sort_rows(
    const int* __restrict__ nnz, int* __restrict__ perm,
    int* __restrict__ cnts) {
  __shared__ int nl[NH];
  const int j = threadIdx.x;
  const int my = nnz[j];
  nl[j] = my;
  __syncthreads();
  int r = 0;
  const int4* p4 = (const int4*)nl;
  for (int i = 0; i < NH / 4; ++i) {
    int4 v = p4[i];
    const int base = i * 4;
    r += (v.x > my) || (v.x == my && base + 0 < j);
    r += (v.y > my) || (v.y == my && base + 1 < j);
    r += (v.z > my) || (v.z == my && base + 2 < j);
    r += (v.w > my) || (v.w == my && base + 3 < j);
  }
  perm[r] = j;
  cnts[r] = (my > PAD) ? PAD : my;
}

// ---------------------------------------------------------------------------
// C: compact W_hh rows into sorted-position-major padded sparse form.
// vals[e*NH + p] = e-th nonzero of row perm[p]; offs = its column.
// ---------------------------------------------------------------------------
__global__ __launch_bounds__(512) void build_sparse(
    const float* __restrict__ Whh, const int* __restrict__ perm,
    float* __restrict__ vals, unsigned* __restrict__ offs) {
  const int wib  = threadIdx.x >> 6;
  const int lane = threadIdx.x & 63;
  const int p    = blockIdx.x * 8 + wib;      // sorted position
  const int row  = perm[p];
  const float* wrow = Whh + (size_t)row * NH;
  int cnt = 0;
  for (int c = 0; c < NH / 64; ++c) {
    float w = wrow[c * 64 + lane];
    unsigned long long m = __ballot(w != 0.0f);
    if (w != 0.0f) {
      int pos = cnt + __popcll(m & ((1ull << lane) - 1ull));
      if (pos < PAD) {
        vals[pos * NH + p] = w;
        offs[pos * NH + p] = (unsigned)(c * 64 + lane);
      }
    }
    cnt += __popcll(m);
  }
  for (int e = cnt + lane; e < PAD; e += 64) {   // zero-pad tail
    vals[e * NH + p] = 0.0f;
    offs[e * NH + p] = 0u;
  }
}

// ---------------------------------------------------------------------------
// Main: one block per batch, 512 threads, 2048 sequential steps.
// ---------------------------------------------------------------------------
__global__ __launch_bounds__(512, 2) void esn_steps(
    const float* __restrict__ x,   const float* __restrict__ h0,
    const float* __restrict__ Wih, const float* __restrict__ Whz,
    const float* __restrict__ Wzh, const float* __restrict__ vals,
    const unsigned* __restrict__ offs, const int* __restrict__ perm,
    const int* __restrict__ cnts, float* __restrict__ out) {
  __shared__ float t_lds[2][NH];              // tanh(h), double-buffered
  __shared__ float x_lds[TT];                 // this batch's input row
  __shared__ __align__(16) float red[2][8];   // cross-wave partials for z

  const int p    = threadIdx.x;               // sorted position owned
  const int b    = blockIdx.x;
  const int lane = p & 63;
  const int wid  = p >> 6;
  const int row  = perm[p];                   // actual hidden unit

  for (int i = p; i < TT; i += NH) x_lds[i] = x[(size_t)b * TT + i];

  // wave-uniform gather trip count: sorted descending -> wave's first
  // position holds the wave max. Round up to the 4-wide unroll.
  int cw = __builtin_amdgcn_readfirstlane(cnts[(p >> 6) << 6]);
  cw = (cw + 3) & ~3;
  if (cw > PAD) cw = PAD;

  // this row's sparse entries -> registers (entry-major, coalesced)
  float    wval[PAD];
  unsigned woff[PADH];                        // two u16 columns per reg
  #pragma unroll
  for (int e = 0; e < PAD; ++e) wval[e] = vals[e * NH + p];
  #pragma unroll
  for (int ep = 0; ep < PADH; ++ep) {
    unsigned lo = offs[(2 * ep) * NH + p];
    unsigned hi = offs[(2 * ep + 1) * NH + p];
    woff[ep] = lo | (hi << 16);
  }

  const float w_ih = Wih[row];
  const float w_hz = Whz[row];
  const float w_zh = Wzh[row];
  float h = h0[(size_t)b * NH + row];

  float* oz = out + (size_t)b * TT;                        // z region [B,T,1]
  float* oh = out + (size_t)BB * TT + (size_t)b * TT * NH; // h region [B,T,NH]

  // ---- init: t[0] = tanh(h0); z_prev = sum(tanh(h0) * Whz) ----
  float th0 = tanhf(h);
  t_lds[0][row] = th0;
  float pz = th0 * w_hz;
  #pragma unroll
  for (int o = 32; o > 0; o >>= 1) pz += __shfl_xor(pz, o);
  if (lane == 0) red[0][wid] = pz;
  __syncthreads();
  float4 i0 = *(const float4*)&red[0][0];
  float4 i1 = *(const float4*)&red[0][4];
  float z_prev = ((i0.x + i0.y) + (i0.z + i0.w)) + ((i1.x + i1.y) + (i1.z + i1.w));

  // ---- 2048 sequential steps, one barrier each ----
  for (int s = 0; s < TT; ++s) {
    const int rd = s & 1, wr = rd ^ 1;

    float d0 = 0.f, d1 = 0.f, d2 = 0.f, d3 = 0.f;
    #pragma unroll
    for (int e = 0; e < PAD; e += 4) {
      if (e >= cw) break;                     // wave-uniform scalar branch
      unsigned p0 = woff[e >> 1];
      unsigned p1 = woff[(e >> 1) + 1];
      d0 = fmaf(wval[e],     t_lds[rd][p0 & 0xFFFFu], d0);
      d1 = fmaf(wval[e + 1], t_lds[rd][p0 >> 16],     d1);
      d2 = fmaf(wval[e + 2], t_lds[rd][p1 & 0xFFFFu], d2);
      d3 = fmaf(wval[e + 3], t_lds[rd][p1 >> 16],     d3);
    }
    float dot = (d0 + d1) + (d2 + d3);

    float xp   = x_lds[s] * w_ih;
    float dhdt = ((dot - h) + xp) + z_prev * w_zh;
    float hn   = h + 0.1f * dhdt;             // alpha = dt/tau = 0.1
    float thn  = tanhf(hn);

    t_lds[wr][row] = thn;                     // scatter (unique indices)
    oh[s * NH + row] = hn;                    // global scatter within 2KB

    float pzs = thn * w_hz;
    #pragma unroll
    for (int o = 32; o > 0; o >>= 1) pzs += __shfl_xor(pzs, o);
    if (lane == 0) red[wr][wid] = pzs;

    __syncthreads();

    float4 r0 = *(const float4*)&red[wr][0];
    float4 r1 = *(const float4*)&red[wr][4];
    float z = ((r0.x + r0.y) + (r0.z + r0.w)) + ((r1.x + r1.y) + (r1.z + r1.w));
    if (p == 0) oz[s] = z;

    z_prev = z;
    h = hn;
  }
}

// ---------------------------------------------------------------------------
extern "C" void kernel_launch(void* const* d_in, const int* in_sizes, int n_in,
                              void* d_out, int out_size, void* d_ws,
                              size_t ws_size, hipStream_t stream) {
  const float* x   = (const float*)d_in[0];
  const float* h0  = (const float*)d_in[1];
  const float* Wih = (const float*)d_in[2];
  const float* Whh = (const float*)d_in[3];
  const float* Whz = (const float*)d_in[4];
  const float* Wzh = (const float*)d_in[5];
  float* out = (float*)d_out;

  float*    vals = (float*)d_ws;                     // PAD*NH f32
  unsigned* offs = (unsigned*)(vals + PAD * NH);     // PAD*NH u32
  int*      nnz  = (int*)(offs + PAD * NH);          // NH
  int*      perm = nnz + NH;                         // NH
  int*      cnts = perm + NH;                        // NH

  hipLaunchKernelGGL(count_nnz, dim3(NH / 8), dim3(512), 0, stream, Whh, nnz);
  hipLaunchKernelGGL(sort_rows, dim3(1), dim3(512), 0, stream, nnz, perm, cnts);
  hipLaunchKernelGGL(build_sparse, dim3(NH / 8), dim3(512), 0, stream,
                     Whh, perm, vals, offs);
  hipLaunchKernelGGL(esn_steps, dim3(BB), dim3(512), 0, stream,
                     x, h0, Wih, Whz, Wzh, vals, offs, perm, cnts, out);
}

// Round 3
// 3784.068 us; speedup vs baseline: 2.8147x; 2.8147x over previous
//
#include <hip/hip_runtime.h>

// Echo-state RNN, B=32, T=2048, NH=512, NI=NO=1.  W_hh ~90% exact zeros.
// One workgroup (CU) per batch; thread p owns the row at SORTED position p
// (rows sorted by nnz desc), so each wave's gather trip count is its local
// max. Sparse rows live in REGISTERS (statically-indexed, guard per 8-chunk
// is a wave-uniform scalar branch -- NO break, which round 2 showed spills
// everything to scratch). Entries within a row are ordered by LDS bank
// distance from the owning lane's home bank to spread gather banks.
// z-reduction via DPP adds (VALU pipe) instead of shuffles (DS pipe).

#define NH   512
#define TT   2048
#define BB   32
#define PAD  88
#define PADH (PAD/2)

// ---------------------------------------------------------------------------
// A: nnz per row (wave-per-row ballot count)
// ---------------------------------------------------------------------------
__global__ __launch_bounds__(512) void count_nnz(
    const float* __restrict__ Whh, int* __restrict__ nnz) {
  const int wib  = threadIdx.x >> 6;
  const int lane = threadIdx.x & 63;
  const int row  = blockIdx.x * 8 + wib;
  const float* wrow = Whh + (size_t)row * NH;
  int cnt = 0;
  for (int c = 0; c < NH / 64; ++c)
    cnt += __popcll(__ballot(wrow[c * 64 + lane] != 0.0f));
  if (lane == 0) nnz[row] = cnt;
}

// ---------------------------------------------------------------------------
// B: rank rows by nnz descending (stable). perm[p] = row at sorted pos p.
// ---------------------------------------------------------------------------
__global__ __launch_bounds__(512) void sort_rows(
    const int* __restrict__ nnz, int* __restrict__ perm,
    int* __restrict__ cnts) {
  __shared__ int nl[NH];
  const int j = threadIdx.x;
  const int my = nnz[j];
  nl[j] = my;
  __syncthreads();
  int r = 0;
  const int4* p4 = (const int4*)nl;
  for (int i = 0; i < NH / 4; ++i) {
    int4 v = p4[i];
    const int base = i * 4;
    r += (v.x > my) || (v.x == my && base + 0 < j);
    r += (v.y > my) || (v.y == my && base + 1 < j);
    r += (v.z > my) || (v.z == my && base + 2 < j);
    r += (v.w > my) || (v.w == my && base + 3 < j);
  }
  perm[r] = j;
  cnts[r] = (my > PAD) ? PAD : my;
}

// ---------------------------------------------------------------------------
// C: compact W_hh row perm[p] into entry-major padded sparse form, entries
// ordered by bank distance d = (bank(col) - home(p)) mod 32 so that at each
// gather slot the wave's 64 lanes hit spread-out banks.
// ---------------------------------------------------------------------------
__global__ __launch_bounds__(512) void build_sparse(
    const float* __restrict__ Whh, const int* __restrict__ perm,
    float* __restrict__ vals, unsigned* __restrict__ offs) {
  const int wib  = threadIdx.x >> 6;
  const int lane = threadIdx.x & 63;
  const int p    = blockIdx.x * 8 + wib;      // sorted position
  const int row  = perm[p];
  const int home = (p & 63) >> 1;             // owning lane's home bank
  const float* wrow = Whh + (size_t)row * NH;
  int cnt = 0;
  for (int r = 0; r < 8; ++r) {
    const int i   = r * 64 + lane;            // scan index 0..511, (d,m) order
    const int d   = i >> 4;                   // bank distance 0..31
    const int m   = i & 15;                   // which of the 16 cols in bank
    const int col = ((home + d) & 31) + m * 32;
    float w = wrow[col];
    unsigned long long msk = __ballot(w != 0.0f);
    if (w != 0.0f) {
      int pos = cnt + __popcll(msk & ((1ull << lane) - 1ull));
      if (pos < PAD) {
        vals[pos * NH + p] = w;
        offs[pos * NH + p] = (unsigned)col;
      }
    }
    cnt += __popcll(msk);
  }
  for (int e = cnt + lane; e < PAD; e += 64) {  // pad: val=0, off=0 (broadcast)
    vals[e * NH + p] = 0.0f;
    offs[e * NH + p] = 0u;
  }
}

// ---------------------------------------------------------------------------
// DPP wave-64 sum reduction on the VALU pipe; lane 63 ends with the full sum.
// ---------------------------------------------------------------------------
template <int CTRL, int RM>
__device__ __forceinline__ float dppadd(float v) {
  int t = __builtin_amdgcn_update_dpp(0, __float_as_int(v), CTRL, RM, 0xF, true);
  return v + __int_as_float(t);
}
__device__ __forceinline__ float wave_sum_lane63(float v) {
  v = dppadd<0xB1,  0xF>(v);   // quad_perm [1,0,3,2]  : xor 1
  v = dppadd<0x4E,  0xF>(v);   // quad_perm [2,3,0,1]  : xor 2
  v = dppadd<0x141, 0xF>(v);   // row_half_mirror      : pair quads
  v = dppadd<0x140, 0xF>(v);   // row_mirror           : pair octets
  v = dppadd<0x142, 0xA>(v);   // row_bcast15 -> rows 1,3
  v = dppadd<0x143, 0xC>(v);   // row_bcast31 -> rows 2,3
  return v;                    // lane 63 = sum of 64
}

// ---------------------------------------------------------------------------
// Main: one block per batch, 512 threads, 2048 sequential steps.
// ---------------------------------------------------------------------------
__global__ __launch_bounds__(512, 2) void esn_steps(
    const float* __restrict__ x,   const float* __restrict__ h0,
    const float* __restrict__ Wih, const float* __restrict__ Whz,
    const float* __restrict__ Wzh, const float* __restrict__ vals,
    const unsigned* __restrict__ offs, const int* __restrict__ perm,
    const int* __restrict__ cnts, float* __restrict__ out) {
  __shared__ float t_lds[2][NH];              // tanh(h), double-buffered
  __shared__ float x_lds[TT];                 // this batch's input row
  __shared__ __align__(16) float red[2][8];   // cross-wave partials for z

  const int p    = threadIdx.x;               // sorted position owned
  const int b    = blockIdx.x;
  const int lane = p & 63;
  const int wid  = p >> 6;
  const int row  = perm[p];                   // actual hidden unit

  for (int i = p; i < TT; i += NH) x_lds[i] = x[(size_t)b * TT + i];

  // wave-uniform gather trip count (sorted desc -> wave's first pos = max),
  // rounded up to the 8-wide chunking of the static unroll.
  int cw = __builtin_amdgcn_readfirstlane(cnts[(p >> 6) << 6]);
  cw = (cw + 7) & ~7;

  // this row's sparse entries -> registers (entry-major, coalesced loads)
  float    wval[PAD];
  unsigned woff[PADH];                        // two u16 columns per reg
  #pragma unroll
  for (int e = 0; e < PAD; ++e) wval[e] = vals[e * NH + p];
  #pragma unroll
  for (int ep = 0; ep < PADH; ++ep) {
    unsigned lo = offs[(2 * ep) * NH + p];
    unsigned hi = offs[(2 * ep + 1) * NH + p];
    woff[ep] = lo | (hi << 16);
  }

  const float w_ih = Wih[row];
  const float w_hz = Whz[row];
  const float w_zh = Wzh[row];
  float h = h0[(size_t)b * NH + row];

  float* oz = out + (size_t)b * TT;                        // z region [B,T,1]
  float* oh = out + (size_t)BB * TT + (size_t)b * TT * NH; // h region [B,T,NH]

  // ---- init: t[0] = tanh(h0); z_prev = sum(tanh(h0) * Whz) ----
  float th0 = tanhf(h);
  t_lds[0][row] = th0;
  float pz = wave_sum_lane63(th0 * w_hz);
  if (lane == 63) red[0][wid] = pz;
  __syncthreads();
  float4 i0 = *(const float4*)&red[0][0];
  float4 i1 = *(const float4*)&red[0][4];
  float z_prev = ((i0.x + i0.y) + (i0.z + i0.w)) + ((i1.x + i1.y) + (i1.z + i1.w));

  // ---- 2048 sequential steps, one barrier each ----
  for (int s = 0; s < TT; ++s) {
    const int rd = s & 1, wr = rd ^ 1;
    const float* t_rd = t_lds[rd];

    // sparse dot; fully static unroll, each 8-chunk guarded by a
    // wave-uniform scalar branch (NO data-dependent break -> no spill).
    float d0 = 0.f, d1 = 0.f, d2 = 0.f, d3 = 0.f;
    #pragma unroll
    for (int e = 0; e < PAD; e += 8) {
      if (e < cw) {
        const unsigned q0 = woff[(e >> 1) + 0];
        const unsigned q1 = woff[(e >> 1) + 1];
        const unsigned q2 = woff[(e >> 1) + 2];
        const unsigned q3 = woff[(e >> 1) + 3];
        d0 = fmaf(wval[e + 0], t_rd[q0 & 0xFFFFu], d0);
        d1 = fmaf(wval[e + 1], t_rd[q0 >> 16],     d1);
        d2 = fmaf(wval[e + 2], t_rd[q1 & 0xFFFFu], d2);
        d3 = fmaf(wval[e + 3], t_rd[q1 >> 16],     d3);
        d0 = fmaf(wval[e + 4], t_rd[q2 & 0xFFFFu], d0);
        d1 = fmaf(wval[e + 5], t_rd[q2 >> 16],     d1);
        d2 = fmaf(wval[e + 6], t_rd[q3 & 0xFFFFu], d2);
        d3 = fmaf(wval[e + 7], t_rd[q3 >> 16],     d3);
      }
    }
    float dot = (d0 + d1) + (d2 + d3);

    float xp   = x_lds[s] * w_ih;
    float dhdt = ((dot - h) + xp) + z_prev * w_zh;
    float hn   = h + 0.1f * dhdt;             // alpha = dt/tau = 0.1
    float thn  = tanhf(hn);

    t_lds[wr][row] = thn;                     // scatter (unique indices)
    oh[s * NH + row] = hn;                    // global scatter within 2KB

    float pzs = wave_sum_lane63(thn * w_hz);  // VALU-pipe reduction
    if (lane == 63) red[wr][wid] = pzs;

    __syncthreads();

    float4 r0 = *(const float4*)&red[wr][0];
    float4 r1 = *(const float4*)&red[wr][4];
    float z = ((r0.x + r0.y) + (r0.z + r0.w)) + ((r1.x + r1.y) + (r1.z + r1.w));
    if (p == 0) oz[s] = z;

    z_prev = z;
    h = hn;
  }
}

// ---------------------------------------------------------------------------
extern "C" void kernel_launch(void* const* d_in, const int* in_sizes, int n_in,
                              void* d_out, int out_size, void* d_ws,
                              size_t ws_size, hipStream_t stream) {
  const float* x   = (const float*)d_in[0];
  const float* h0  = (const float*)d_in[1];
  const float* Wih = (const float*)d_in[2];
  const float* Whh = (const float*)d_in[3];
  const float* Whz = (const float*)d_in[4];
  const float* Wzh = (const float*)d_in[5];
  float* out = (float*)d_out;

  float*    vals = (float*)d_ws;                     // PAD*NH f32
  unsigned* offs = (unsigned*)(vals + PAD * NH);     // PAD*NH u32
  int*      nnz  = (int*)(offs + PAD * NH);          // NH
  int*      perm = nnz + NH;                         // NH
  int*      cnts = perm + NH;                        // NH

  hipLaunchKernelGGL(count_nnz, dim3(NH / 8), dim3(512), 0, stream, Whh, nnz);
  hipLaunchKernelGGL(sort_rows, dim3(1), dim3(512), 0, stream, nnz, perm, cnts);
  hipLaunchKernelGGL(build_sparse, dim3(NH / 8), dim3(512), 0, stream,
                     Whh, perm, vals, offs);
  hipLaunchKernelGGL(esn_steps, dim3(BB), dim3(512), 0, stream,
                     x, h0, Wih, Whz, Wzh, vals, offs, perm, cnts, out);
}